// Round 11
// baseline (720.888 us; speedup 1.0000x reference)
//
#include <hip/hip_runtime.h>
#include <hip/hip_bf16.h>

#define N_NODES 50000
#define N_EDGES 1600000
#define NREL    16
#define DIM     64

#define NBKT    391           // coarse buckets of 128 dst nodes (proven p1)
#define SBN     3125          // fine buckets of 16 dst nodes (= 50000/16)
#define P1_CHUNK 2048
#define P1_GRID  782          // ceil(1.6M/2048)

#define GPAD    1036          // 1024 + 12 floats: 16-B aligned, 2-way banks

typedef __attribute__((ext_vector_type(8))) short short8;
typedef __attribute__((ext_vector_type(4))) float float4v;

template<int IS_F32>
__device__ __forceinline__ float ldx(const void* p, size_t i) {
    if (IS_F32) {
        return ((const float*)p)[i];
    } else {
        unsigned short u = ((const unsigned short*)p)[i];
        return __uint_as_float(((unsigned)u) << 16);
    }
}

__device__ __forceinline__ float bfbits2f(unsigned short u) {
    return __uint_as_float(((unsigned)u) << 16);
}

__device__ __forceinline__ unsigned short f2bfbits(float v) {
    __hip_bfloat16 b = __float2bfloat16(v);
    unsigned short us; __builtin_memcpy(&us, &b, 2);
    return us;
}

// ---------------------------------------------------------------------------
// Dtype detector (proven): flag=1 if f32 dataset, 0 if bf16.
// ---------------------------------------------------------------------------
__global__ __launch_bounds__(1024) void k_detect(
    const float* __restrict__ norm_f, int* __restrict__ flag)
{
    __shared__ int sbad;
    if (threadIdx.x == 0) sbad = 0;
    __syncthreads();
    float v = norm_f[threadIdx.x];
    int bad = (v != v || fabsf(v) > 1e3f) ? 1 : 0;
    if (bad) atomicOr(&sbad, 1);
    __syncthreads();
    if (threadIdx.x == 0) *flag = sbad ? 0 : 1;
}

// ---------------------------------------------------------------------------
// Bucket histogram (proven, atomic-free at global scope).
// ---------------------------------------------------------------------------
__global__ __launch_bounds__(256) void k_bhist(
    const int* __restrict__ dst, int* __restrict__ H)
{
    __shared__ int hist[NBKT];
    for (int i = threadIdx.x; i < NBKT; i += 256) hist[i] = 0;
    __syncthreads();
    const int e0 = blockIdx.x * P1_CHUNK;
    for (int i = threadIdx.x; i < P1_CHUNK; i += 256) {
        int e = e0 + i;
        if (e < N_EDGES) atomicAdd(&hist[dst[e] >> 7], 1);
    }
    __syncthreads();
    for (int b = threadIdx.x; b < NBKT; b += 256)
        H[blockIdx.x * NBKT + b] = hist[b];
}

__global__ __launch_bounds__(256) void k_bscan1(
    const int* __restrict__ H, int* __restrict__ OT, int* __restrict__ tot)
{
    __shared__ int col[P1_GRID];
    const int b = blockIdx.x;
    for (int i = threadIdx.x; i < P1_GRID; i += 256)
        col[i] = H[i * NBKT + b];
    __syncthreads();
    if (threadIdx.x < 64) {
        const int lane = threadIdx.x;
        int carry = 0;
        for (int chunk = 0; chunk < (P1_GRID + 63) / 64; ++chunk) {
            int i = chunk * 64 + lane;
            int c = (i < P1_GRID) ? col[i] : 0;
            int incl = c;
#pragma unroll
            for (int off = 1; off < 64; off <<= 1) {
                int t = __shfl_up(incl, off, 64);
                if (lane >= off) incl += t;
            }
            if (i < P1_GRID) col[i] = carry + incl - c;
            carry += __shfl(incl, 63, 64);
        }
        if (lane == 0) tot[b] = carry;
    }
    __syncthreads();
    for (int i = threadIdx.x; i < P1_GRID; i += 256)
        OT[(size_t)b * P1_GRID + i] = col[i];
}

__global__ __launch_bounds__(64) void k_bscan2(
    const int* __restrict__ tot, int* __restrict__ base)
{
    const int lane = threadIdx.x;
    int carry = 0;
    for (int chunk = 0; chunk < (NBKT + 63) / 64; ++chunk) {
        int i = chunk * 64 + lane;
        int c = (i < NBKT) ? tot[i] : 0;
        int incl = c;
#pragma unroll
        for (int off = 1; off < 64; off <<= 1) {
            int t = __shfl_up(incl, off, 64);
            if (lane >= off) incl += t;
        }
        if (i < NBKT) base[i] = carry + incl - c;
        carry += __shfl(incl, 63, 64);
    }
    if (lane == 0) base[NBKT] = carry;   // == N_EDGES
}

// ---------------------------------------------------------------------------
// Wb prep: W[k][o] -> B-fragment layout Wb[((S*4+q)*64 + o)*8 + j],
// k = 32S + 8q + j. One 16-B load per MFMA B-frag, L2-hot (128 KB).
// ---------------------------------------------------------------------------
template<int IS_F32>
__device__ __forceinline__ void wprep_body(
    const void* __restrict__ w_raw, unsigned short* __restrict__ Wb)
{
    int idx = blockIdx.x * 256 + threadIdx.x;   // 0..65535
    int k = idx >> 6, o = idx & 63;
    int S = k >> 5, q = (k >> 3) & 3, j = k & 7;
    float wv = ldx<IS_F32>(w_raw, (size_t)k * 64 + o);
    Wb[(size_t)(((S * 4 + q) * 64 + o) * 8 + j)] = f2bfbits(wv);
}

__global__ __launch_bounds__(256) void k_wprep(
    const void* __restrict__ w_raw, unsigned short* __restrict__ Wb,
    const int* __restrict__ flag)
{
    if (*flag) wprep_body<1>(w_raw, Wb);
    else       wprep_body<0>(w_raw, Wb);
}

// ---------------------------------------------------------------------------
// P1 (proven): multisplit into 391 coarse bucket runs, deterministic.
// rec: [7:0]=dst&127, [23:8]=src, [27:24]=rel, [47:32]=norm bf16.
// ---------------------------------------------------------------------------
template<int IS_F32>
__device__ __forceinline__ void p1_body(
    const int* __restrict__ src, const int* __restrict__ dst,
    const int* __restrict__ rel, const void* __restrict__ norm_raw,
    const int* __restrict__ base, const int* __restrict__ OT,
    unsigned long long* __restrict__ R, int* curs)
{
    const int blk = blockIdx.x;
    for (int b = threadIdx.x; b < NBKT; b += 256)
        curs[b] = base[b] + OT[(size_t)b * P1_GRID + blk];
    __syncthreads();
    const int e0 = blk * P1_CHUNK;
    for (int i = threadIdx.x; i < P1_CHUNK; i += 256) {
        int e = e0 + i;
        if (e >= N_EDGES) continue;
        int d = dst[e];
        int pos = atomicAdd(&curs[d >> 7], 1);
        unsigned short nb = f2bfbits(ldx<IS_F32>(norm_raw, e));
        unsigned long long rec =
              (unsigned long long)(d & 127)
            | ((unsigned long long)(unsigned)src[e] << 8)
            | ((unsigned long long)(unsigned)rel[e] << 24)
            | ((unsigned long long)nb << 32);
        R[pos] = rec;
    }
}

__global__ __launch_bounds__(256) void k_p1(
    const int* __restrict__ src, const int* __restrict__ dst,
    const int* __restrict__ rel, const void* __restrict__ norm_raw,
    const int* __restrict__ base, const int* __restrict__ OT,
    unsigned long long* __restrict__ R, const int* __restrict__ flag)
{
    __shared__ int curs[NBKT];
    if (*flag) p1_body<1>(src, dst, rel, norm_raw, base, OT, R, curs);
    else       p1_body<0>(src, dst, rel, norm_raw, base, OT, R, curs);
}

// ---------------------------------------------------------------------------
// P2-lite: per coarse bucket, split records into 8 sub-buckets of 16 nodes
// (block-private contiguous writes). Emits SB[] sub-bucket boundaries.
// ---------------------------------------------------------------------------
__global__ __launch_bounds__(256) void k_p2lite(
    const int* __restrict__ base,
    const unsigned long long* __restrict__ R,
    unsigned long long* __restrict__ R2,
    int* __restrict__ SB)
{
    __shared__ int cnt[8];
    __shared__ int pref[8];
    __shared__ int curs[8];
    const int tid = threadIdx.x;
    if (tid < 8) cnt[tid] = 0;
    __syncthreads();

    const int b  = blockIdx.x;
    const int c0 = base[b], c1 = base[b + 1];
    const int n0 = b << 7;
    const int nn = min(128, N_NODES - n0);
    const int nsb = (nn + 15) >> 4;

    for (int i = c0 + tid; i < c1; i += 256)
        atomicAdd(&cnt[((int)(R[i] & 127)) >> 4], 1);
    __syncthreads();

    if (tid == 0) {
        int r = 0;
#pragma unroll
        for (int s = 0; s < 8; ++s) { pref[s] = r; r += cnt[s]; }
    }
    __syncthreads();
    if (tid < 8) curs[tid] = c0 + pref[tid];
    if (tid < nsb) SB[(b << 3) + tid] = c0 + pref[tid];
    if (b == NBKT - 1 && tid == 0) SB[SBN] = c1;
    __syncthreads();

    for (int i = c0 + tid; i < c1; i += 256) {
        unsigned long long rec = R[i];
        int pos = atomicAdd(&curs[((int)(rec & 127)) >> 4], 1);
        R2[pos] = rec;
    }
}

// ---------------------------------------------------------------------------
// K_FUSED: per 16-node fine bucket: (1) zero fp32 g-tile in LDS,
// (2) gather edges: gt[node&15][rel*64+d] += norm * h[src][d] (LDS atomics,
// order-free), (3) MFMA the tile vs Wb, fused relu + store. g never touches
// global memory — kills the 205 MB g stream.
// ---------------------------------------------------------------------------
template<int IS_F32>
__device__ __forceinline__ void fused_body(
    const unsigned long long* __restrict__ R2,
    const int* __restrict__ SB,
    const void* __restrict__ h_raw,
    const unsigned short* __restrict__ Wb,
    void* __restrict__ out,
    float* gt)
{
    const int tid  = threadIdx.x;
    const int lane = tid & 63, wave = tid >> 6;
    const int n15  = lane & 15, quad = lane >> 4;
    const int b2   = blockIdx.x;
    const int node0 = b2 * 16;

    for (int i = tid; i < 16 * 1024; i += 256)
        gt[(i >> 10) * GPAD + (i & 1023)] = 0.f;
    __syncthreads();

    const int start = __builtin_amdgcn_readfirstlane(SB[b2]);
    const int end   = __builtin_amdgcn_readfirstlane(SB[b2 + 1]);

    int i = start + wave;
    for (; i + 28 < end; i += 32) {          // 8-deep, stride 4 waves
        unsigned long long rc[8];
        float hv[8];
#pragma unroll
        for (int m = 0; m < 8; ++m) rc[m] = R2[i + m * 4];
#pragma unroll
        for (int m = 0; m < 8; ++m)
            hv[m] = ldx<IS_F32>(h_raw, (size_t)((rc[m] >> 8) & 0xFFFFu) * DIM + lane);
#pragma unroll
        for (int m = 0; m < 8; ++m) {
            float nv = bfbits2f((unsigned short)(rc[m] >> 32));
            int nl = (int)(rc[m] & 15);
            int rl = (int)((rc[m] >> 24) & 15);
            atomicAdd(&gt[nl * GPAD + rl * 64 + lane], hv[m] * nv);
        }
    }
    for (; i < end; i += 4) {
        unsigned long long rc = R2[i];
        float hv = ldx<IS_F32>(h_raw, (size_t)((rc >> 8) & 0xFFFFu) * DIM + lane);
        float nv = bfbits2f((unsigned short)(rc >> 32));
        int nl = (int)(rc & 15), rl = (int)((rc >> 24) & 15);
        atomicAdd(&gt[nl * GPAD + rl * 64 + lane], hv * nv);
    }
    __syncthreads();

    // GEMM: wave t = n-tile (cols t*16..t*16+15), K = 1024 in 32 steps.
    // A[m=n15][k=s*32+quad*8+j] from LDS; B-frag = one 16-B load from Wb.
    float4v acc = (float4v){0.f, 0.f, 0.f, 0.f};
    const int t = wave;
    for (int s = 0; s < 32; ++s) {
        float f[8];
#pragma unroll
        for (int j = 0; j < 8; ++j)
            f[j] = gt[n15 * GPAD + s * 32 + quad * 8 + j];
        short8 af;
#pragma unroll
        for (int j = 0; j < 8; ++j) af[j] = (short)f2bfbits(f[j]);
        const short8* bf = (const short8*)&Wb[(size_t)(((s * 4 + quad) * 64 + t * 16 + n15) * 8)];
        acc = __builtin_amdgcn_mfma_f32_16x16x32_bf16(af, *bf, acc, 0, 0, 0);
    }

#pragma unroll
    for (int ii = 0; ii < 4; ++ii) {
        int node = node0 + quad * 4 + ii;     // C row m = quad*4 + reg
        float r = fmaxf(acc[ii], 0.f);
        size_t ob = (size_t)node * DIM + t * 16 + n15;
        if (IS_F32) ((float*)out)[ob] = r;
        else        ((unsigned short*)out)[ob] = f2bfbits(r);
    }
}

__global__ __launch_bounds__(256) void k_fused(
    const unsigned long long* __restrict__ R2,
    const int* __restrict__ SB,
    const void* __restrict__ h_raw,
    const unsigned short* __restrict__ Wb,
    void* __restrict__ out,
    const int* __restrict__ flag)
{
    __shared__ float gt[16 * GPAD];   // 66.3 KB -> 2 blocks/CU
    if (*flag) fused_body<1>(R2, SB, h_raw, Wb, out, gt);
    else       fused_body<0>(R2, SB, h_raw, Wb, out, gt);
}

// ---------------------------------------------------------------------------
extern "C" void kernel_launch(void* const* d_in, const int* in_sizes, int n_in,
                              void* d_out, int out_size, void* d_ws, size_t ws_size,
                              hipStream_t stream)
{
    const void* h      = d_in[0];
    const void* weight = d_in[1];
    const void* norm   = d_in[2];
    const int* src = (const int*)d_in[3];
    const int* dst = (const int*)d_in[4];
    const int* rel = (const int*)d_in[5];

    // ws: flag(256) | base[392] | tot[391] | SB[3126] | Wb 128KB | H | OT
    //     | R u64[E] | R2 u64[E]
    char* w = (char*)d_ws;
    int*   flag = (int*)w;                      w += 256;
    int*   base = (int*)w;                      w += 2048;
    int*   tot  = (int*)w;                      w += 2048;
    int*   SB   = (int*)w;                      w += 16384;
    unsigned short* Wb = (unsigned short*)w;    w += 131072;
    int*   H    = (int*)w;                      w += (size_t)P1_GRID * NBKT * 4;
    int*   OT   = (int*)w;                      w += (size_t)NBKT * P1_GRID * 4;
    unsigned long long* R  = (unsigned long long*)w; w += (size_t)N_EDGES * 8;
    unsigned long long* R2 = (unsigned long long*)w;

    k_detect<<<1, 1024, 0, stream>>>((const float*)norm, flag);

    k_bhist<<<P1_GRID, 256, 0, stream>>>(dst, H);
    k_bscan1<<<NBKT, 256, 0, stream>>>(H, OT, tot);
    k_bscan2<<<1, 64, 0, stream>>>(tot, base);
    k_wprep<<<256, 256, 0, stream>>>(weight, Wb, flag);

    k_p1<<<P1_GRID, 256, 0, stream>>>(src, dst, rel, norm, base, OT, R, flag);
    k_p2lite<<<NBKT, 256, 0, stream>>>(base, R, R2, SB);

    k_fused<<<SBN, 256, 0, stream>>>(R2, SB, h, Wb, d_out, flag);
}

// Round 13
// 264.386 us; speedup vs baseline: 2.7267x; 2.7267x over previous
//
#include <hip/hip_runtime.h>
#include <hip/hip_bf16.h>

#define N_NODES 50000
#define N_EDGES 1600000
#define NREL    16
#define DIM     64

#define NBKT    391           // ceil(50000/128) buckets of 128 dst nodes
#define P1_CHUNK 2048
#define P1_GRID  782          // ceil(1.6M/2048)

typedef __attribute__((ext_vector_type(8))) short short8;
typedef __attribute__((ext_vector_type(4))) float float4v;

template<int IS_F32>
__device__ __forceinline__ float ldx(const void* p, size_t i) {
    if (IS_F32) {
        return ((const float*)p)[i];
    } else {
        unsigned short u = ((const unsigned short*)p)[i];
        return __uint_as_float(((unsigned)u) << 16);
    }
}

__device__ __forceinline__ float bfbits2f(unsigned short u) {
    return __uint_as_float(((unsigned)u) << 16);
}

__device__ __forceinline__ unsigned short f2bfbits(float v) {
    __hip_bfloat16 b = __float2bfloat16(v);
    unsigned short us; __builtin_memcpy(&us, &b, 2);
    return us;
}

// ---------------------------------------------------------------------------
// Dtype detector (proven standalone): flag=1 if f32 dataset, 0 if bf16.
// ---------------------------------------------------------------------------
__global__ __launch_bounds__(1024) void k_detect(
    const float* __restrict__ norm_f, int* __restrict__ flag)
{
    __shared__ int sbad;
    if (threadIdx.x == 0) sbad = 0;
    __syncthreads();
    float v = norm_f[threadIdx.x];
    int bad = (v != v || fabsf(v) > 1e3f) ? 1 : 0;
    if (bad) atomicOr(&sbad, 1);
    __syncthreads();
    if (threadIdx.x == 0) *flag = sbad ? 0 : 1;
}

// ---------------------------------------------------------------------------
// Bucket histogram (proven, atomic-free at global scope).
// ---------------------------------------------------------------------------
__global__ __launch_bounds__(256) void k_bhist(
    const int* __restrict__ dst, int* __restrict__ H)
{
    __shared__ int hist[NBKT];
    for (int i = threadIdx.x; i < NBKT; i += 256) hist[i] = 0;
    __syncthreads();
    const int e0 = blockIdx.x * P1_CHUNK;
    for (int i = threadIdx.x; i < P1_CHUNK; i += 256) {
        int e = e0 + i;
        if (e < N_EDGES) atomicAdd(&hist[dst[e] >> 7], 1);
    }
    __syncthreads();
    for (int b = threadIdx.x; b < NBKT; b += 256)
        H[blockIdx.x * NBKT + b] = hist[b];
}

__global__ __launch_bounds__(256) void k_bscan1(
    const int* __restrict__ H, int* __restrict__ OT, int* __restrict__ tot)
{
    __shared__ int col[P1_GRID];
    const int b = blockIdx.x;
    for (int i = threadIdx.x; i < P1_GRID; i += 256)
        col[i] = H[i * NBKT + b];
    __syncthreads();
    if (threadIdx.x < 64) {
        const int lane = threadIdx.x;
        int carry = 0;
        for (int chunk = 0; chunk < (P1_GRID + 63) / 64; ++chunk) {
            int i = chunk * 64 + lane;
            int c = (i < P1_GRID) ? col[i] : 0;
            int incl = c;
#pragma unroll
            for (int off = 1; off < 64; off <<= 1) {
                int t = __shfl_up(incl, off, 64);
                if (lane >= off) incl += t;
            }
            if (i < P1_GRID) col[i] = carry + incl - c;
            carry += __shfl(incl, 63, 64);
        }
        if (lane == 0) tot[b] = carry;
    }
    __syncthreads();
    for (int i = threadIdx.x; i < P1_GRID; i += 256)
        OT[(size_t)b * P1_GRID + i] = col[i];
}

__global__ __launch_bounds__(64) void k_bscan2(
    const int* __restrict__ tot, int* __restrict__ base)
{
    const int lane = threadIdx.x;
    int carry = 0;
    for (int chunk = 0; chunk < (NBKT + 63) / 64; ++chunk) {
        int i = chunk * 64 + lane;
        int c = (i < NBKT) ? tot[i] : 0;
        int incl = c;
#pragma unroll
        for (int off = 1; off < 64; off <<= 1) {
            int t = __shfl_up(incl, off, 64);
            if (lane >= off) incl += t;
        }
        if (i < NBKT) base[i] = carry + incl - c;
        carry += __shfl(incl, 63, 64);
    }
    if (lane == 0) base[NBKT] = carry;   // == N_EDGES
}

// ---------------------------------------------------------------------------
// P1 (proven): multisplit into bucket runs, deterministic reservation.
// rec: [7:0]=dst&127, [23:8]=src, [27:24]=rel, [47:32]=norm bf16.
// ---------------------------------------------------------------------------
template<int IS_F32>
__device__ __forceinline__ void p1_body(
    const int* __restrict__ src, const int* __restrict__ dst,
    const int* __restrict__ rel, const void* __restrict__ norm_raw,
    const int* __restrict__ base, const int* __restrict__ OT,
    unsigned long long* __restrict__ R, int* curs)
{
    const int blk = blockIdx.x;
    for (int b = threadIdx.x; b < NBKT; b += 256)
        curs[b] = base[b] + OT[(size_t)b * P1_GRID + blk];
    __syncthreads();
    const int e0 = blk * P1_CHUNK;
    for (int i = threadIdx.x; i < P1_CHUNK; i += 256) {
        int e = e0 + i;
        if (e >= N_EDGES) continue;
        int d = dst[e];
        int pos = atomicAdd(&curs[d >> 7], 1);
        unsigned short nb = f2bfbits(ldx<IS_F32>(norm_raw, e));
        unsigned long long rec =
              (unsigned long long)(d & 127)
            | ((unsigned long long)(unsigned)src[e] << 8)
            | ((unsigned long long)(unsigned)rel[e] << 24)
            | ((unsigned long long)nb << 32);
        R[pos] = rec;
    }
}

__global__ __launch_bounds__(256) void k_p1(
    const int* __restrict__ src, const int* __restrict__ dst,
    const int* __restrict__ rel, const void* __restrict__ norm_raw,
    const int* __restrict__ base, const int* __restrict__ OT,
    unsigned long long* __restrict__ R, const int* __restrict__ flag)
{
    __shared__ int curs[NBKT];
    if (*flag) p1_body<1>(src, dst, rel, norm_raw, base, OT, R, curs);
    else       p1_body<0>(src, dst, rel, norm_raw, base, OT, R, curs);
}

// ---------------------------------------------------------------------------
// P2 (proven): per-bucket exact CSR placement + A[] emission.
// ---------------------------------------------------------------------------
__global__ __launch_bounds__(256) void k_p2(
    const int* __restrict__ base,
    const unsigned long long* __restrict__ R,
    unsigned* __restrict__ packed,
    unsigned short* __restrict__ normS,
    int* __restrict__ A)
{
    __shared__ int cnt[128];
    __shared__ int Aex[128];
    __shared__ int curs[128];
    __shared__ int tot0s;
    const int tid = threadIdx.x;
    if (tid < 128) { cnt[tid] = 0; curs[tid] = 0; }
    __syncthreads();

    const int b  = blockIdx.x;
    const int n0 = b << 7;
    const int nn = min(128, N_NODES - n0);
    const int c0 = base[b], c1 = base[b + 1];

    for (int i = c0 + tid; i < c1; i += 256)
        atomicAdd(&cnt[(int)(R[i] & 127)], 1);
    __syncthreads();

    if (tid < 64) {
        int c = cnt[tid], incl = c;
#pragma unroll
        for (int off = 1; off < 64; off <<= 1) {
            int t = __shfl_up(incl, off, 64);
            if (tid >= off) incl += t;
        }
        Aex[tid] = c0 + incl - c;
        if (tid == 63) tot0s = incl;
    }
    __syncthreads();
    if (tid >= 64 && tid < 128) {
        int lane = tid - 64;
        int c = cnt[tid], incl = c;
#pragma unroll
        for (int off = 1; off < 64; off <<= 1) {
            int t = __shfl_up(incl, off, 64);
            if (lane >= off) incl += t;
        }
        Aex[tid] = c0 + tot0s + incl - c;
    }
    __syncthreads();

    if (tid < nn) A[n0 + tid] = Aex[tid];
    if (b == NBKT - 1 && tid == 0) A[N_NODES] = c1;

    for (int i = c0 + tid; i < c1; i += 256) {
        unsigned long long rec = R[i];
        int nl = (int)(rec & 127);
        int pos = Aex[nl] + atomicAdd(&curs[nl], 1);
        packed[pos] = (unsigned)((rec >> 8) & 0xFFFFFFu);
        normS[pos]  = (unsigned short)(rec >> 32);
    }
}

// ---------------------------------------------------------------------------
// K1 (MFMA, proven R8): node tile 256/block, W swizzle amortized 4x.
// Plain stores (NT reverted — post-timing race suspect in R12).
// ---------------------------------------------------------------------------
template<int IS_F32>
__device__ __forceinline__ short8 load_afrag(const void* h_raw, int row, int quad, int half)
{
    short8 r;
    if (IS_F32) {
        const float4* p = (const float4*)((const char*)h_raw + (size_t)row * 256 + half * 128 + quad * 32);
        float4 f0 = p[0], f1 = p[1];
        float fv[8] = {f0.x, f0.y, f0.z, f0.w, f1.x, f1.y, f1.z, f1.w};
#pragma unroll
        for (int j = 0; j < 8; ++j) r[j] = (short)f2bfbits(fv[j]);
    } else {
        uint4 v = *(const uint4*)((const char*)h_raw + (size_t)row * 128 + half * 64 + quad * 16);
        __builtin_memcpy(&r, &v, 16);
    }
    return r;
}

template<int IS_F32>
__device__ __forceinline__ void mfma_body(
    const void* __restrict__ h_raw,
    const void* __restrict__ w_raw,
    __hip_bfloat16* __restrict__ transformed,
    short* Wl)
{
    const int lane = threadIdx.x & 63;
    const int wave = threadIdx.x >> 6;
    const int n15  = lane & 15;
    const int quad = lane >> 4;
    const int rbase = blockIdx.y * 4;

    for (int idx = threadIdx.x; idx < 4 * 64 * 64; idx += 256) {
        int o = idx & 63, d = (idx >> 6) & 63, rl = idx >> 12;
        float wv = ldx<IS_F32>(w_raw, (size_t)((rbase + rl) * 64 + d) * 64 + o);
        int c = d >> 5, q = (d >> 3) & 3, j = d & 7;
        Wl[((rl * 2 + c) * 64 + o) * 40 + q * 8 + j] = (short)f2bfbits(wv);
    }
    __syncthreads();

    unsigned short* tb = (unsigned short*)transformed;
    const int node_blk = blockIdx.x * 256;

    for (int ng = 0; ng < 4; ++ng) {
        const int node0 = node_blk + ng * 64 + wave * 16;
        if (node0 >= N_NODES) continue;   // 50000 % 16 == 0

        short8 a0 = load_afrag<IS_F32>(h_raw, node0 + n15, quad, 0);
        short8 a1 = load_afrag<IS_F32>(h_raw, node0 + n15, quad, 1);

#pragma unroll
        for (int rl = 0; rl < 4; ++rl) {
            float4v acc[4];
#pragma unroll
            for (int t = 0; t < 4; ++t) acc[t] = (float4v){0.f, 0.f, 0.f, 0.f};

#pragma unroll
            for (int t = 0; t < 4; ++t) {
                const short8* b0 = (const short8*)&Wl[((rl * 2 + 0) * 64 + t * 16 + n15) * 40 + quad * 8];
                acc[t] = __builtin_amdgcn_mfma_f32_16x16x32_bf16(a0, *b0, acc[t], 0, 0, 0);
            }
#pragma unroll
            for (int t = 0; t < 4; ++t) {
                const short8* b1 = (const short8*)&Wl[((rl * 2 + 1) * 64 + t * 16 + n15) * 40 + quad * 8];
                acc[t] = __builtin_amdgcn_mfma_f32_16x16x32_bf16(a1, *b1, acc[t], 0, 0, 0);
            }

            const int r = rbase + rl;
#pragma unroll
            for (int t = 0; t < 4; ++t) {
#pragma unroll
                for (int i = 0; i < 4; ++i) {
                    int node = node0 + quad * 4 + i;
                    tb[((size_t)node * NREL + r) * DIM + t * 16 + n15] = f2bfbits(acc[t][i]);
                }
            }
        }
    }
}

__global__ __launch_bounds__(256) void k1_mfma(
    const void* __restrict__ h_raw,
    const void* __restrict__ w_raw,
    __hip_bfloat16* __restrict__ transformed,
    const int* __restrict__ flag)
{
    __shared__ short Wl[4 * 2 * 64 * 40];   // 40 KB
    if (*flag) mfma_body<1>(h_raw, w_raw, transformed, Wl);
    else       mfma_body<0>(h_raw, w_raw, transformed, Wl);
}

// ---------------------------------------------------------------------------
// K_ACC: one wave per dst node; 8-deep gather pipeline (8 x 128 B in flight
// per wave). Plain loads (NT reverted).
// ---------------------------------------------------------------------------
template<int IS_F32>
__device__ __forceinline__ void acc_body(
    const unsigned* __restrict__ packed,
    const unsigned short* __restrict__ normS,
    const __hip_bfloat16* __restrict__ transformed,
    const int* __restrict__ A,
    void* __restrict__ out)
{
    const int lane = threadIdx.x & 63;
    const int v = blockIdx.x * 4 + (threadIdx.x >> 6);
    if (v >= N_NODES) return;

    const int start = __builtin_amdgcn_readfirstlane(A[v]);
    const int end   = __builtin_amdgcn_readfirstlane(A[v + 1]);

    const unsigned short* tb = (const unsigned short*)transformed;
    float a = 0.f;
    int i = start;
    for (; i + 8 <= end; i += 8) {
        unsigned u[8];
        float    n[8];
        unsigned off[8];
        float    t[8];
#pragma unroll
        for (int m = 0; m < 8; ++m) u[m] = packed[i + m];
#pragma unroll
        for (int m = 0; m < 8; ++m) n[m] = bfbits2f(normS[i + m]);
#pragma unroll
        for (int m = 0; m < 8; ++m)
            off[m] = ((u[m] & 0xFFFFu) * NREL + (u[m] >> 16)) * DIM + lane;
#pragma unroll
        for (int m = 0; m < 8; ++m) t[m] = bfbits2f(tb[off[m]]);
#pragma unroll
        for (int m = 0; m < 8; ++m) a = fmaf(t[m], n[m], a);
    }
    for (; i + 4 <= end; i += 4) {
        unsigned u0 = packed[i],     u1 = packed[i + 1];
        unsigned u2 = packed[i + 2], u3 = packed[i + 3];
        float n0 = bfbits2f(normS[i]),     n1 = bfbits2f(normS[i + 1]);
        float n2 = bfbits2f(normS[i + 2]), n3 = bfbits2f(normS[i + 3]);
        unsigned off0 = ((u0 & 0xFFFFu) * NREL + (u0 >> 16)) * DIM + lane;
        unsigned off1 = ((u1 & 0xFFFFu) * NREL + (u1 >> 16)) * DIM + lane;
        unsigned off2 = ((u2 & 0xFFFFu) * NREL + (u2 >> 16)) * DIM + lane;
        unsigned off3 = ((u3 & 0xFFFFu) * NREL + (u3 >> 16)) * DIM + lane;
        float t0 = bfbits2f(tb[off0]);
        float t1 = bfbits2f(tb[off1]);
        float t2 = bfbits2f(tb[off2]);
        float t3 = bfbits2f(tb[off3]);
        a = fmaf(t0, n0, a);
        a = fmaf(t1, n1, a);
        a = fmaf(t2, n2, a);
        a = fmaf(t3, n3, a);
    }
    for (; i < end; ++i) {
        unsigned u0 = packed[i];
        float n0 = bfbits2f(normS[i]);
        unsigned off0 = ((u0 & 0xFFFFu) * NREL + (u0 >> 16)) * DIM + lane;
        a = fmaf(bfbits2f(tb[off0]), n0, a);
    }

    float r = fmaxf(a, 0.f);
    const size_t ob = (size_t)v * DIM + lane;
    if (IS_F32) {
        ((float*)out)[ob] = r;
    } else {
        ((unsigned short*)out)[ob] = f2bfbits(r);
    }
}

__global__ __launch_bounds__(256) void k_acc(
    const unsigned* __restrict__ packed,
    const unsigned short* __restrict__ normS,
    const __hip_bfloat16* __restrict__ transformed,
    const int* __restrict__ A,
    void* __restrict__ out, const int* __restrict__ flag)
{
    if (*flag) acc_body<1>(packed, normS, transformed, A, out);
    else       acc_body<0>(packed, normS, transformed, A, out);
}

// ---------------------------------------------------------------------------
extern "C" void kernel_launch(void* const* d_in, const int* in_sizes, int n_in,
                              void* d_out, int out_size, void* d_ws, size_t ws_size,
                              hipStream_t stream)
{
    const void* h      = d_in[0];
    const void* weight = d_in[1];
    const void* norm   = d_in[2];
    const int* src = (const int*)d_in[3];
    const int* dst = (const int*)d_in[4];
    const int* rel = (const int*)d_in[5];

    // ws: flag(256) | A[50001] | base | tot | H | OT | packed u32[E]
    //     | normS u16[E] | transformed bf16[N*R*64]  (R u64[E] aliases
    //     transformed; consumed by k_p2 before k1_mfma writes — stream order)
    char* w = (char*)d_ws;
    int*   flag = (int*)w;                      w += 256;
    int*   A    = (int*)w;                      w += 200192;
    int*   base = (int*)w;                      w += 2048;
    int*   tot  = (int*)w;                      w += 2048;
    int*   H    = (int*)w;                      w += (size_t)P1_GRID * NBKT * 4;
    int*   OT   = (int*)w;                      w += (size_t)NBKT * P1_GRID * 4;
    unsigned* packed = (unsigned*)w;            w += (size_t)N_EDGES * 4;
    unsigned short* normS = (unsigned short*)w; w += (size_t)N_EDGES * 2;
    __hip_bfloat16* transformed = (__hip_bfloat16*)w;
    unsigned long long* R = (unsigned long long*)transformed;

    k_detect<<<1, 1024, 0, stream>>>((const float*)norm, flag);

    k_bhist<<<P1_GRID, 256, 0, stream>>>(dst, H);
    k_bscan1<<<NBKT, 256, 0, stream>>>(H, OT, tot);
    k_bscan2<<<1, 64, 0, stream>>>(tot, base);

    k_p1<<<P1_GRID, 256, 0, stream>>>(src, dst, rel, norm, base, OT, R, flag);
    k_p2<<<NBKT, 256, 0, stream>>>(base, R, packed, normS, A);

    dim3 g1((N_NODES + 255) / 256, 4);
    k1_mfma<<<g1, 256, 0, stream>>>(h, weight, transformed, flag);

    k_acc<<<12500, 256, 0, stream>>>(packed, normS, transformed, A, d_out, flag);
}